// Round 15
// baseline (900.527 us; speedup 1.0000x reference)
//
#include <hip/hip_runtime.h>
#include <hip/hip_bf16.h>

#define N_NODES 100000
#define E_EDGES 1600000
#define HID 128
#define LN_EPS 1e-5f
#define SCAN_CHUNK 1024
#define NB_SCAN ((N_NODES + SCAN_CHUNK - 1) / SCAN_CHUNK)  // 98

typedef __attribute__((ext_vector_type(8))) __bf16 bf16x8;
typedef __attribute__((ext_vector_type(4))) float f32x4;
typedef __attribute__((ext_vector_type(8))) unsigned short u16x8;

__device__ __forceinline__ unsigned short f2bf(float v) {
    __hip_bfloat16 h = __float2bfloat16(v);
    return __builtin_bit_cast(unsigned short, h);
}
__device__ __forceinline__ float bf2f(unsigned short us) {
    unsigned int v = ((unsigned int)us) << 16;
    return __builtin_bit_cast(float, v);
}

// ---------------- CSR build ----------------
__global__ __launch_bounds__(256)
void k_hist(const int* __restrict__ eidx, int* __restrict__ deg) {
    int e = blockIdx.x * 256 + threadIdx.x;
    if (e < E_EDGES) atomicAdd(&deg[eidx[E_EDGES + e]], 1);
}

// pack node positions into contiguous float2 (L2-resident)
__global__ __launch_bounds__(256)
void k_pos(const float* __restrict__ x, float2* __restrict__ pos2) {
    int c = blockIdx.x * 256 + threadIdx.x;
    if (c < N_NODES)
        pos2[c] = make_float2(x[(size_t)c * 130 + 128], x[(size_t)c * 130 + 129]);
}

__global__ __launch_bounds__(256)
void k_scan1(const int* __restrict__ deg, int* __restrict__ bsum) {
    __shared__ int s[256];
    int b = blockIdx.x, t = threadIdx.x;
    int sum = 0;
#pragma unroll
    for (int i = 0; i < 4; ++i) {
        int idx = b * SCAN_CHUNK + i * 256 + t;
        sum += (idx < N_NODES) ? deg[idx] : 0;
    }
    s[t] = sum; __syncthreads();
    for (int off = 128; off > 0; off >>= 1) {
        if (t < off) s[t] += s[t + off];
        __syncthreads();
    }
    if (t == 0) bsum[b] = s[0];
}

__global__ __launch_bounds__(256)
void k_scan2(int* __restrict__ bsum, int* __restrict__ offsets) {
    __shared__ int s[256];
    int t = threadIdx.x;
    int v = (t < NB_SCAN) ? bsum[t] : 0;
    s[t] = v; __syncthreads();
    for (int off = 1; off < 256; off <<= 1) {
        int add = (t >= off) ? s[t - off] : 0;
        __syncthreads();
        s[t] += add;
        __syncthreads();
    }
    if (t < NB_SCAN) bsum[t] = s[t] - v;
    if (t == NB_SCAN - 1) offsets[N_NODES] = s[t];
}

__global__ __launch_bounds__(256)
void k_scan3(const int* __restrict__ deg, const int* __restrict__ bsum,
             int* __restrict__ offsets) {
    __shared__ int s[256];
    int b = blockIdx.x, t = threadIdx.x;
    int base = b * SCAN_CHUNK + t * 4;
    int v[4]; int sum = 0;
#pragma unroll
    for (int i = 0; i < 4; ++i) {
        v[i] = (base + i < N_NODES) ? deg[base + i] : 0;
        sum += v[i];
    }
    s[t] = sum; __syncthreads();
    for (int off = 1; off < 256; off <<= 1) {
        int add = (t >= off) ? s[t - off] : 0;
        __syncthreads();
        s[t] += add;
        __syncthreads();
    }
    int toff = bsum[b] + s[t] - sum;
#pragma unroll
    for (int i = 0; i < 4; ++i) {
        if (base + i < N_NODES) offsets[base + i] = toff;
        toff += v[i];
    }
}

// fill: also precompute per-edge (dx,dy) into CSR slot (kills the eidx/pos chain in gather)
__global__ __launch_bounds__(256)
void k_fill(const int* __restrict__ eidx, const int* __restrict__ offsets,
            const float2* __restrict__ pos2,
            int* __restrict__ cursor, int* __restrict__ elist,
            float2* __restrict__ dxy) {
    int e = blockIdx.x * 256 + threadIdx.x;
    if (e >= E_EDGES) return;
    int c = eidx[E_EDGES + e];
    int r = eidx[e];
    int pos = atomicAdd(&cursor[c], 1);
    int slot = offsets[c] + pos;
    elist[slot] = e;
    float2 pc = pos2[c], pr = pos2[r];
    dxy[slot] = make_float2(pc.x - pr.x, pc.y - pr.y);
}

// ---------------- W2 repack only: fragment-ordered bf16 hi + lo (r7-verified) ----------------
__global__ __launch_bounds__(256)
void k_prep2(const float* __restrict__ W2,
             unsigned short* __restrict__ W2ph, unsigned short* __restrict__ W2pl)
{
    int t = blockIdx.x * 256 + threadIdx.x;
    if (t < 4 * 8 * 64 * 8) {   // 16384
        int j = t & 7, l = (t >> 3) & 63;
        int rest = t >> 9;
        int f = rest & 7, kc = rest >> 3;
        int k = kc * 32 + (l >> 4) * 8 + j;
        float w = W2[(size_t)k * 128 + f * 16 + (l & 15)];
        unsigned short h = f2bf(w);
        W2ph[t] = h;
        W2pl[t] = f2bf(w - bf2f(h));
    }
}

// ---------------- Gather: r12 loop shape, chain shortened to elist -> edge_attr ----------------
__global__ __launch_bounds__(256)
void k_gather(const float2* __restrict__ dxy,
              const float* __restrict__ edge_attr,
              const float* __restrict__ W_proj,
              const float* __restrict__ b_proj,
              const int* __restrict__ offsets,
              const int* __restrict__ elist,
              float* m_i,
              float* __restrict__ curl)
{
    __shared__ float Wp[HID * 8];
    for (int i = threadIdx.x; i < HID * 8; i += 256) Wp[i] = W_proj[i];
    __syncthreads();

    int wave = threadIdx.x >> 6;
    int lane = threadIdx.x & 63;
    int c = blockIdx.x * 4 + wave;
    if (c >= N_NODES) return;

    int jb = offsets[c];
    int cnt = offsets[c + 1] - jb;

    float m0 = 0, m1 = 0, p0 = 0, p1 = 0, q0 = 0, q1 = 0, sdx = 0, sdy = 0;

    float2 aC = make_float2(0, 0), aN = make_float2(0, 0);
    float2 dC = make_float2(0, 0), dN = make_float2(0, 0);

    if (cnt > 0) {
        int e = elist[jb];
        dC = dxy[jb];
        aC = *(const float2*)(edge_attr + (size_t)e * HID + lane * 2);
    }
    if (cnt > 1) {
        int e = elist[jb + 1];
        dN = dxy[jb + 1];
        aN = *(const float2*)(edge_attr + (size_t)e * HID + lane * 2);
    }

    for (int j = 0; j < cnt; ++j) {
        float2 a = aC; float2 d = dC;
        aC = aN; dC = dN;
        if (j + 2 < cnt) {
            int e = elist[jb + j + 2];
            dN = dxy[jb + j + 2];
            aN = *(const float2*)(edge_attr + (size_t)e * HID + lane * 2);
        }
        m0 += a.x;       m1 += a.y;
        p0 += a.x * d.x; p1 += a.y * d.x;
        q0 -= a.x * d.y; q1 -= a.y * d.y;
        sdx += d.x;      sdy += d.y;
    }

    *(float2*)(m_i + (size_t)c * HID + lane * 2) = make_float2(m0, m1);

    const float* w0 = &Wp[(2 * lane) * 8];
    const float* w1 = &Wp[(2 * lane + 1) * 8];
    float part[4];
#pragma unroll
    for (int h = 0; h < 4; ++h)
        part[h] = q0 * w0[2 * h] + p0 * w0[2 * h + 1] + q1 * w1[2 * h] + p1 * w1[2 * h + 1];
#pragma unroll
    for (int m = 1; m < 64; m <<= 1)
#pragma unroll
        for (int h = 0; h < 4; ++h) part[h] += __shfl_xor(part[h], m);

    if (lane == 0) {
#pragma unroll
        for (int h = 0; h < 4; ++h)
            curl[(size_t)c * 4 + h] = part[h] - b_proj[2 * h] * sdy + b_proj[2 * h + 1] * sdx;
    }
}

// ---------------- Node kernel HYBRID: GEMM1 = fp32 VALU, GEMM2 = MFMA (r12 verbatim) ----------------
__global__ __launch_bounds__(256)
void node_hyb(const float* __restrict__ x,
              const float* m_i,                    // aliases out (own rows only)
              const float* __restrict__ curl,
              const float* __restrict__ u,
              const int* __restrict__ batch,
              const float* __restrict__ W1,
              const float* __restrict__ b1,
              const float* __restrict__ ln_g, const float* __restrict__ ln_b,
              const unsigned short* __restrict__ W2ph,
              const unsigned short* __restrict__ W2pl,
              const float* __restrict__ b2,
              float* out)
{
    __shared__ float Af[32 * 396];          // [hE 0..127 | m_i 128..255 | tau 256..383]
    __shared__ unsigned short Sm[32 * 136]; // bf16 SiLU'd tile
    __shared__ float2 pss[32][2];
    __shared__ float curl_s[32 * 4];

    const int tid = threadIdx.x;
    const int base = blockIdx.x * 32;

    for (int idx = tid; idx < 32 * 64; idx += 256) {   // h_E via float2
        int n = idx >> 6, g = idx & 63;
        int node = base + n;
        float2 v = make_float2(0.f, 0.f);
        if (node < N_NODES) v = *(const float2*)(x + (size_t)node * 130 + g * 2);
        *(float2*)&Af[n * 396 + g * 2] = v;
    }
    for (int idx = tid; idx < 32 * 32; idx += 256) {   // m_i
        int n = idx >> 5, g = idx & 31;
        int node = base + n;
        float4 v = make_float4(0.f, 0.f, 0.f, 0.f);
        if (node < N_NODES) v = *(const float4*)(m_i + (size_t)node * 128 + g * 4);
        *(float4*)&Af[n * 396 + 128 + g * 4] = v;
    }
    for (int idx = tid; idx < 32 * 32; idx += 256) {   // tau
        int n = idx >> 5, g = idx & 31;
        int node = base + n;
        float4 v = make_float4(0.f, 0.f, 0.f, 0.f);
        if (node < N_NODES) v = *(const float4*)(u + (size_t)batch[node] * 128 + g * 4);
        *(float4*)&Af[n * 396 + 256 + g * 4] = v;
    }
    for (int idx = tid; idx < 32 * 4; idx += 256) {    // curl scalar
        int node = base + (idx >> 2);
        curl_s[idx] = (node < N_NODES) ? curl[(size_t)node * 4 + (idx & 3)] : 0.f;
    }
    __syncthreads();

    const int lane = tid & 63;
    const int wave = tid >> 6;
    const int band = wave >> 1;
    const int fh   = wave & 1;
    const int cg = lane >> 4, cl = lane & 15;
    const int rowA = band * 16 + cl;
    const int nl0  = band * 16 + cg * 4;

    const float* a0 = &Af[(nl0 + 0) * 396];
    const float* a1 = &Af[(nl0 + 1) * 396];
    const float* a2 = &Af[(nl0 + 2) * 396];
    const float* a3 = &Af[(nl0 + 3) * 396];

    // GEMM1: fp32 VALU (verified passing)
    f32x4 acc[4];
#pragma unroll
    for (int f = 0; f < 4; ++f) {
        int col = (fh * 4 + f) * 16 + cl;
        float s0 = 0.f, s1 = 0.f, s2 = 0.f, s3 = 0.f;
        for (int k = 0; k < 256; ++k) {
            float w = W1[(size_t)k * 128 + col];
            s0 += a0[k] * w; s1 += a1[k] * w; s2 += a2[k] * w; s3 += a3[k] * w;
        }
        for (int k = 256; k < 384; ++k) {
            float w = W1[(size_t)(k + 4) * 128 + col];
            s0 += a0[k] * w; s1 += a1[k] * w; s2 += a2[k] * w; s3 += a3[k] * w;
        }
        acc[f] = (f32x4){s0, s1, s2, s3};
    }

    // curl rank-4 update + bias (verified)
#pragma unroll
    for (int f = 0; f < 4; ++f) {
        int col = (fh * 4 + f) * 16 + cl;
        float w0 = W1[(size_t)256 * 128 + col];
        float w1 = W1[(size_t)257 * 128 + col];
        float w2 = W1[(size_t)258 * 128 + col];
        float w3 = W1[(size_t)259 * 128 + col];
        float bb = b1[col];
#pragma unroll
        for (int r = 0; r < 4; ++r) {
            const float* cs = &curl_s[(nl0 + r) * 4];
            acc[f][r] += bb + cs[0] * w0 + cs[1] * w1 + cs[2] * w2 + cs[3] * w3;
        }
    }

    // LN partials (verified)
    float sA[4], ssA[4];
#pragma unroll
    for (int r = 0; r < 4; ++r) {
        float s = 0.f, ss = 0.f;
#pragma unroll
        for (int f = 0; f < 4; ++f) { float h = acc[f][r]; s += h; ss += h * h; }
#pragma unroll
        for (int m = 1; m < 16; m <<= 1) {
            s  += __shfl_xor(s, m);
            ss += __shfl_xor(ss, m);
        }
        sA[r] = s; ssA[r] = ss;
    }
    if (cl == 0) {
#pragma unroll
        for (int r = 0; r < 4; ++r) pss[nl0 + r][fh] = make_float2(sA[r], ssA[r]);
    }
    __syncthreads();

    float gvv[4], bvv[4];
#pragma unroll
    for (int f = 0; f < 4; ++f) {
        int col = (fh * 4 + f) * 16 + cl;
        gvv[f] = ln_g[col]; bvv[f] = ln_b[col];
    }

#pragma unroll
    for (int r = 0; r < 4; ++r) {
        float2 p0 = pss[nl0 + r][0], p1 = pss[nl0 + r][1];
        float s = p0.x + p1.x, ss = p0.y + p1.y;
        float mu  = s * (1.f / 128.f);
        float var = ss * (1.f / 128.f) - mu * mu;
        float inv = rsqrtf(var + LN_EPS);
#pragma unroll
        for (int f = 0; f < 4; ++f) {
            float h = (acc[f][r] - mu) * inv * gvv[f] + bvv[f];
            h = h / (1.f + expf(-h));
            Sm[(nl0 + r) * 136 + (fh * 4 + f) * 16 + cl] = f2bf(h);
        }
    }
    __syncthreads();

    // GEMM2: split-bf16 MFMA block (verified, verbatim)
    f32x4 acc2[4];
#pragma unroll
    for (int f = 0; f < 4; ++f) acc2[f] = (f32x4){0.f, 0.f, 0.f, 0.f};

#pragma unroll
    for (int kc = 0; kc < 4; ++kc) {
        u16x8 araw = *(const u16x8*)&Sm[rowA * 136 + kc * 32 + cg * 8];
        bf16x8 AS = __builtin_bit_cast(bf16x8, araw);
#pragma unroll
        for (int f = 0; f < 4; ++f) {
            size_t fo = ((size_t)(kc * 8 + fh * 4 + f) * 64 + lane) * 8;
            bf16x8 BH = __builtin_bit_cast(bf16x8, *(const u16x8*)(W2ph + fo));
            bf16x8 BL = __builtin_bit_cast(bf16x8, *(const u16x8*)(W2pl + fo));
            acc2[f] = __builtin_amdgcn_mfma_f32_16x16x32_bf16(AS, BH, acc2[f], 0, 0, 0);
            acc2[f] = __builtin_amdgcn_mfma_f32_16x16x32_bf16(AS, BL, acc2[f], 0, 0, 0);
        }
    }

#pragma unroll
    for (int f = 0; f < 4; ++f) {
        int col = (fh * 4 + f) * 16 + cl;
        float bb = b2[col];
#pragma unroll
        for (int r = 0; r < 4; ++r) {
            int node = base + nl0 + r;
            if (node < N_NODES) out[(size_t)node * 128 + col] = acc2[f][r] + bb;
        }
    }
}

extern "C" void kernel_launch(void* const* d_in, const int* in_sizes, int n_in,
                              void* d_out, int out_size, void* d_ws, size_t ws_size,
                              hipStream_t stream) {
    const float* x         = (const float*)d_in[0];
    const int*   eidx      = (const int*)d_in[1];
    const float* edge_attr = (const float*)d_in[2];
    const float* u         = (const float*)d_in[3];
    const int*   batch     = (const int*)d_in[4];
    const float* W_proj    = (const float*)d_in[5];
    const float* b_proj    = (const float*)d_in[6];
    const float* W1        = (const float*)d_in[7];
    const float* b1        = (const float*)d_in[8];
    const float* ln_g      = (const float*)d_in[9];
    const float* ln_b      = (const float*)d_in[10];
    const float* W2        = (const float*)d_in[11];
    const float* b2        = (const float*)d_in[12];

    float* out = (float*)d_out;

    // ws carve-out: byte-identical offsets to r12; dxy appended at the end.
    char* p = (char*)d_ws;
    size_t off = 0;
    auto take = [&](size_t bytes) {
        char* q = p + off;
        off += (bytes + 255) & ~(size_t)255;
        return q;
    };
    (void)take(49152 * 2);   // reserved (keeps offsets identical to r12)
    (void)take(49152 * 2);   // reserved
    unsigned short* W2ph = (unsigned short*)take(16384 * 2);
    unsigned short* W2pl = (unsigned short*)take(16384 * 2);
    int* deg     = (int*)take(N_NODES * 4);
    int* cursor  = (int*)take(N_NODES * 4);
    int* offsets = (int*)take((N_NODES + 1) * 4);
    int* bsum    = (int*)take(256 * 4);
    int* elist   = (int*)take((size_t)E_EDGES * 4);
    float* curl  = (float*)take((size_t)N_NODES * 4 * 4);
    float2* pos2 = (float2*)take((size_t)N_NODES * 8);
    float2* dxy  = (float2*)take((size_t)E_EDGES * 8);

    hipMemsetAsync(deg, 0, (size_t)N_NODES * 4, stream);
    hipMemsetAsync(cursor, 0, (size_t)N_NODES * 4, stream);

    k_prep2<<<64, 256, 0, stream>>>(W2, W2ph, W2pl);
    k_pos  <<<(N_NODES + 255) / 256, 256, 0, stream>>>(x, pos2);
    k_hist <<<(E_EDGES + 255) / 256, 256, 0, stream>>>(eidx, deg);
    k_scan1<<<NB_SCAN, 256, 0, stream>>>(deg, bsum);
    k_scan2<<<1, 256, 0, stream>>>(bsum, offsets);
    k_scan3<<<NB_SCAN, 256, 0, stream>>>(deg, bsum, offsets);
    k_fill <<<(E_EDGES + 255) / 256, 256, 0, stream>>>(eidx, offsets, pos2, cursor, elist, dxy);

    k_gather<<<(N_NODES + 3) / 4, 256, 0, stream>>>(
        dxy, edge_attr, W_proj, b_proj, offsets, elist, out, curl);

    node_hyb<<<(N_NODES + 31) / 32, 256, 0, stream>>>(
        x, out, curl, u, batch, W1, b1, ln_g, ln_b, W2ph, W2pl, b2, out);
}

// Round 20
// 886.361 us; speedup vs baseline: 1.0160x; 1.0160x over previous
//
#include <hip/hip_runtime.h>
#include <hip/hip_bf16.h>

#define N_NODES 100000
#define E_EDGES 1600000
#define HID 128
#define LN_EPS 1e-5f
#define SCAN_CHUNK 1024
#define NB_SCAN ((N_NODES + SCAN_CHUNK - 1) / SCAN_CHUNK)  // 98

typedef __attribute__((ext_vector_type(4))) float f32x4;

// ---------------- CSR build ----------------
__global__ __launch_bounds__(256)
void k_hist(const int* __restrict__ eidx, int* __restrict__ deg) {
    int e = blockIdx.x * 256 + threadIdx.x;
    if (e < E_EDGES) atomicAdd(&deg[eidx[E_EDGES + e]], 1);
}

// pack node positions into contiguous float2 (L2-resident)
__global__ __launch_bounds__(256)
void k_pos(const float* __restrict__ x, float2* __restrict__ pos2) {
    int c = blockIdx.x * 256 + threadIdx.x;
    if (c < N_NODES)
        pos2[c] = make_float2(x[(size_t)c * 130 + 128], x[(size_t)c * 130 + 129]);
}

__global__ __launch_bounds__(256)
void k_scan1(const int* __restrict__ deg, int* __restrict__ bsum) {
    __shared__ int s[256];
    int b = blockIdx.x, t = threadIdx.x;
    int sum = 0;
#pragma unroll
    for (int i = 0; i < 4; ++i) {
        int idx = b * SCAN_CHUNK + i * 256 + t;
        sum += (idx < N_NODES) ? deg[idx] : 0;
    }
    s[t] = sum; __syncthreads();
    for (int off = 128; off > 0; off >>= 1) {
        if (t < off) s[t] += s[t + off];
        __syncthreads();
    }
    if (t == 0) bsum[b] = s[0];
}

__global__ __launch_bounds__(256)
void k_scan2(int* __restrict__ bsum, int* __restrict__ offsets) {
    __shared__ int s[256];
    int t = threadIdx.x;
    int v = (t < NB_SCAN) ? bsum[t] : 0;
    s[t] = v; __syncthreads();
    for (int off = 1; off < 256; off <<= 1) {
        int add = (t >= off) ? s[t - off] : 0;
        __syncthreads();
        s[t] += add;
        __syncthreads();
    }
    if (t < NB_SCAN) bsum[t] = s[t] - v;
    if (t == NB_SCAN - 1) offsets[N_NODES] = s[t];
}

__global__ __launch_bounds__(256)
void k_scan3(const int* __restrict__ deg, const int* __restrict__ bsum,
             int* __restrict__ offsets) {
    __shared__ int s[256];
    int b = blockIdx.x, t = threadIdx.x;
    int base = b * SCAN_CHUNK + t * 4;
    int v[4]; int sum = 0;
#pragma unroll
    for (int i = 0; i < 4; ++i) {
        v[i] = (base + i < N_NODES) ? deg[base + i] : 0;
        sum += v[i];
    }
    s[t] = sum; __syncthreads();
    for (int off = 1; off < 256; off <<= 1) {
        int add = (t >= off) ? s[t - off] : 0;
        __syncthreads();
        s[t] += add;
        __syncthreads();
    }
    int toff = bsum[b] + s[t] - sum;
#pragma unroll
    for (int i = 0; i < 4; ++i) {
        if (base + i < N_NODES) offsets[base + i] = toff;
        toff += v[i];
    }
}

// fill: also precompute per-edge (dx,dy) into CSR slot (kills the eidx/pos chain in gather)
__global__ __launch_bounds__(256)
void k_fill(const int* __restrict__ eidx, const int* __restrict__ offsets,
            const float2* __restrict__ pos2,
            int* __restrict__ cursor, int* __restrict__ elist,
            float2* __restrict__ dxy) {
    int e = blockIdx.x * 256 + threadIdx.x;
    if (e >= E_EDGES) return;
    int c = eidx[E_EDGES + e];
    int r = eidx[e];
    int pos = atomicAdd(&cursor[c], 1);
    int slot = offsets[c] + pos;
    elist[slot] = e;
    float2 pc = pos2[c], pr = pos2[r];
    dxy[slot] = make_float2(pc.x - pr.x, pc.y - pr.y);
}

// ---------------- Gather: r13 verbatim (chain = elist -> edge_attr) ----------------
__global__ __launch_bounds__(256)
void k_gather(const float2* __restrict__ dxy,
              const float* __restrict__ edge_attr,
              const float* __restrict__ W_proj,
              const float* __restrict__ b_proj,
              const int* __restrict__ offsets,
              const int* __restrict__ elist,
              float* m_i,
              float* __restrict__ curl)
{
    __shared__ float Wp[HID * 8];
    for (int i = threadIdx.x; i < HID * 8; i += 256) Wp[i] = W_proj[i];
    __syncthreads();

    int wave = threadIdx.x >> 6;
    int lane = threadIdx.x & 63;
    int c = blockIdx.x * 4 + wave;
    if (c >= N_NODES) return;

    int jb = offsets[c];
    int cnt = offsets[c + 1] - jb;

    float m0 = 0, m1 = 0, p0 = 0, p1 = 0, q0 = 0, q1 = 0, sdx = 0, sdy = 0;

    float2 aC = make_float2(0, 0), aN = make_float2(0, 0);
    float2 dC = make_float2(0, 0), dN = make_float2(0, 0);

    if (cnt > 0) {
        int e = elist[jb];
        dC = dxy[jb];
        aC = *(const float2*)(edge_attr + (size_t)e * HID + lane * 2);
    }
    if (cnt > 1) {
        int e = elist[jb + 1];
        dN = dxy[jb + 1];
        aN = *(const float2*)(edge_attr + (size_t)e * HID + lane * 2);
    }

    for (int j = 0; j < cnt; ++j) {
        float2 a = aC; float2 d = dC;
        aC = aN; dC = dN;
        if (j + 2 < cnt) {
            int e = elist[jb + j + 2];
            dN = dxy[jb + j + 2];
            aN = *(const float2*)(edge_attr + (size_t)e * HID + lane * 2);
        }
        m0 += a.x;       m1 += a.y;
        p0 += a.x * d.x; p1 += a.y * d.x;
        q0 -= a.x * d.y; q1 -= a.y * d.y;
        sdx += d.x;      sdy += d.y;
    }

    *(float2*)(m_i + (size_t)c * HID + lane * 2) = make_float2(m0, m1);

    const float* w0 = &Wp[(2 * lane) * 8];
    const float* w1 = &Wp[(2 * lane + 1) * 8];
    float part[4];
#pragma unroll
    for (int h = 0; h < 4; ++h)
        part[h] = q0 * w0[2 * h] + p0 * w0[2 * h + 1] + q1 * w1[2 * h] + p1 * w1[2 * h + 1];
#pragma unroll
    for (int m = 1; m < 64; m <<= 1)
#pragma unroll
        for (int h = 0; h < 4; ++h) part[h] += __shfl_xor(part[h], m);

    if (lane == 0) {
#pragma unroll
        for (int h = 0; h < 4; ++h)
            curl[(size_t)c * 4 + h] = part[h] - b_proj[2 * h] * sdy + b_proj[2 * h + 1] * sdx;
    }
}

// ---------------- Node kernel: full fp32 VALU (r6 verbatim — 2/2 passes at absmax 0.0039) ----------------
__global__ __launch_bounds__(256)
void node_valu(const float* __restrict__ x,
               const float* m_i,                    // aliases out (own rows only)
               const float* __restrict__ curl,
               const float* __restrict__ u,
               const int* __restrict__ batch,
               const float* __restrict__ W1,
               const float* __restrict__ b1,
               const float* __restrict__ ln_g, const float* __restrict__ ln_b,
               const float* __restrict__ W2,
               const float* __restrict__ b2,
               float* out)
{
    __shared__ float Af[32 * 396];   // [hE 0..127 | m_i 128..255 | tau 256..383]; cols 0..127 reused for S
    __shared__ float2 pss[32][2];
    __shared__ float curl_s[32 * 4];

    const int tid = threadIdx.x;
    const int base = blockIdx.x * 32;

    for (int idx = tid; idx < 32 * 64; idx += 256) {   // h_E via float2
        int n = idx >> 6, g = idx & 63;
        int node = base + n;
        float2 v = make_float2(0.f, 0.f);
        if (node < N_NODES) v = *(const float2*)(x + (size_t)node * 130 + g * 2);
        *(float2*)&Af[n * 396 + g * 2] = v;
    }
    for (int idx = tid; idx < 32 * 32; idx += 256) {   // m_i
        int n = idx >> 5, g = idx & 31;
        int node = base + n;
        float4 v = make_float4(0.f, 0.f, 0.f, 0.f);
        if (node < N_NODES) v = *(const float4*)(m_i + (size_t)node * 128 + g * 4);
        *(float4*)&Af[n * 396 + 128 + g * 4] = v;
    }
    for (int idx = tid; idx < 32 * 32; idx += 256) {   // tau
        int n = idx >> 5, g = idx & 31;
        int node = base + n;
        float4 v = make_float4(0.f, 0.f, 0.f, 0.f);
        if (node < N_NODES) v = *(const float4*)(u + (size_t)batch[node] * 128 + g * 4);
        *(float4*)&Af[n * 396 + 256 + g * 4] = v;
    }
    for (int idx = tid; idx < 32 * 4; idx += 256) {    // curl scalar
        int node = base + (idx >> 2);
        curl_s[idx] = (node < N_NODES) ? curl[(size_t)node * 4 + (idx & 3)] : 0.f;
    }
    __syncthreads();

    const int lane = tid & 63;
    const int wave = tid >> 6;
    const int band = wave >> 1;
    const int fh   = wave & 1;
    const int cg = lane >> 4, cl = lane & 15;
    const int nl0  = band * 16 + cg * 4;

    const float* a0 = &Af[(nl0 + 0) * 396];
    const float* a1 = &Af[(nl0 + 1) * 396];
    const float* a2 = &Af[(nl0 + 2) * 396];
    const float* a3 = &Af[(nl0 + 3) * 396];

    // GEMM1: fp32 VALU
    f32x4 acc[4];
#pragma unroll
    for (int f = 0; f < 4; ++f) {
        int col = (fh * 4 + f) * 16 + cl;
        float s0 = 0.f, s1 = 0.f, s2 = 0.f, s3 = 0.f;
        for (int k = 0; k < 256; ++k) {
            float w = W1[(size_t)k * 128 + col];
            s0 += a0[k] * w; s1 += a1[k] * w; s2 += a2[k] * w; s3 += a3[k] * w;
        }
        for (int k = 256; k < 384; ++k) {
            float w = W1[(size_t)(k + 4) * 128 + col];
            s0 += a0[k] * w; s1 += a1[k] * w; s2 += a2[k] * w; s3 += a3[k] * w;
        }
        acc[f] = (f32x4){s0, s1, s2, s3};
    }

    // curl rank-4 update + bias
#pragma unroll
    for (int f = 0; f < 4; ++f) {
        int col = (fh * 4 + f) * 16 + cl;
        float w0 = W1[(size_t)256 * 128 + col];
        float w1 = W1[(size_t)257 * 128 + col];
        float w2 = W1[(size_t)258 * 128 + col];
        float w3 = W1[(size_t)259 * 128 + col];
        float bb = b1[col];
#pragma unroll
        for (int r = 0; r < 4; ++r) {
            const float* cs = &curl_s[(nl0 + r) * 4];
            acc[f][r] += bb + cs[0] * w0 + cs[1] * w1 + cs[2] * w2 + cs[3] * w3;
        }
    }

    // LN partials
    float sA[4], ssA[4];
#pragma unroll
    for (int r = 0; r < 4; ++r) {
        float s = 0.f, ss = 0.f;
#pragma unroll
        for (int f = 0; f < 4; ++f) { float h = acc[f][r]; s += h; ss += h * h; }
#pragma unroll
        for (int m = 1; m < 16; m <<= 1) {
            s  += __shfl_xor(s, m);
            ss += __shfl_xor(ss, m);
        }
        sA[r] = s; ssA[r] = ss;
    }
    if (cl == 0) {
#pragma unroll
        for (int r = 0; r < 4; ++r) pss[nl0 + r][fh] = make_float2(sA[r], ssA[r]);
    }
    __syncthreads();   // pss ready; all GEMM1 reads of Af complete -> safe to overwrite

    float gvv[4], bvv[4];
#pragma unroll
    for (int f = 0; f < 4; ++f) {
        int col = (fh * 4 + f) * 16 + cl;
        gvv[f] = ln_g[col]; bvv[f] = ln_b[col];
    }

#pragma unroll
    for (int r = 0; r < 4; ++r) {
        float2 p0 = pss[nl0 + r][0], p1 = pss[nl0 + r][1];
        float s = p0.x + p1.x, ss = p0.y + p1.y;
        float mu  = s * (1.f / 128.f);
        float var = ss * (1.f / 128.f) - mu * mu;
        float inv = rsqrtf(var + LN_EPS);
#pragma unroll
        for (int f = 0; f < 4; ++f) {
            float h = (acc[f][r] - mu) * inv * gvv[f] + bvv[f];
            h = h / (1.f + expf(-h));
            Af[(nl0 + r) * 396 + (fh * 4 + f) * 16 + cl] = h;   // S, fp32, in-place
        }
    }
    __syncthreads();

    // GEMM2: fp32 VALU
    f32x4 acc2[4];
#pragma unroll
    for (int f = 0; f < 4; ++f) {
        int col = (fh * 4 + f) * 16 + cl;
        float s0 = 0.f, s1 = 0.f, s2 = 0.f, s3 = 0.f;
        for (int k2 = 0; k2 < 128; ++k2) {
            float w = W2[(size_t)k2 * 128 + col];
            s0 += a0[k2] * w; s1 += a1[k2] * w; s2 += a2[k2] * w; s3 += a3[k2] * w;
        }
        acc2[f] = (f32x4){s0, s1, s2, s3};
    }

#pragma unroll
    for (int f = 0; f < 4; ++f) {
        int col = (fh * 4 + f) * 16 + cl;
        float bb = b2[col];
#pragma unroll
        for (int r = 0; r < 4; ++r) {
            int node = base + nl0 + r;
            if (node < N_NODES) out[(size_t)node * 128 + col] = acc2[f][r] + bb;
        }
    }
}

extern "C" void kernel_launch(void* const* d_in, const int* in_sizes, int n_in,
                              void* d_out, int out_size, void* d_ws, size_t ws_size,
                              hipStream_t stream) {
    const float* x         = (const float*)d_in[0];
    const int*   eidx      = (const int*)d_in[1];
    const float* edge_attr = (const float*)d_in[2];
    const float* u         = (const float*)d_in[3];
    const int*   batch     = (const int*)d_in[4];
    const float* W_proj    = (const float*)d_in[5];
    const float* b_proj    = (const float*)d_in[6];
    const float* W1        = (const float*)d_in[7];
    const float* b1        = (const float*)d_in[8];
    const float* ln_g      = (const float*)d_in[9];
    const float* ln_b      = (const float*)d_in[10];
    const float* W2        = (const float*)d_in[11];
    const float* b2        = (const float*)d_in[12];

    float* out = (float*)d_out;

    // ws carve-out: offsets byte-identical to r13 (pack sections reserved, unused).
    char* p = (char*)d_ws;
    size_t off = 0;
    auto take = [&](size_t bytes) {
        char* q = p + off;
        off += (bytes + 255) & ~(size_t)255;
        return q;
    };
    (void)take(49152 * 2);   // reserved
    (void)take(49152 * 2);   // reserved
    (void)take(16384 * 2);   // reserved (was W2ph)
    (void)take(16384 * 2);   // reserved (was W2pl)
    int* deg     = (int*)take(N_NODES * 4);
    int* cursor  = (int*)take(N_NODES * 4);
    int* offsets = (int*)take((N_NODES + 1) * 4);
    int* bsum    = (int*)take(256 * 4);
    int* elist   = (int*)take((size_t)E_EDGES * 4);
    float* curl  = (float*)take((size_t)N_NODES * 4 * 4);
    float2* pos2 = (float2*)take((size_t)N_NODES * 8);
    float2* dxy  = (float2*)take((size_t)E_EDGES * 8);

    hipMemsetAsync(deg, 0, (size_t)N_NODES * 4, stream);
    hipMemsetAsync(cursor, 0, (size_t)N_NODES * 4, stream);

    k_pos  <<<(N_NODES + 255) / 256, 256, 0, stream>>>(x, pos2);
    k_hist <<<(E_EDGES + 255) / 256, 256, 0, stream>>>(eidx, deg);
    k_scan1<<<NB_SCAN, 256, 0, stream>>>(deg, bsum);
    k_scan2<<<1, 256, 0, stream>>>(bsum, offsets);
    k_scan3<<<NB_SCAN, 256, 0, stream>>>(deg, bsum, offsets);
    k_fill <<<(E_EDGES + 255) / 256, 256, 0, stream>>>(eidx, offsets, pos2, cursor, elist, dxy);

    k_gather<<<(N_NODES + 3) / 4, 256, 0, stream>>>(
        dxy, edge_attr, W_proj, b_proj, offsets, elist, out, curl);

    node_valu<<<(N_NODES + 31) / 32, 256, 0, stream>>>(
        x, out, curl, u, batch, W1, b1, ln_g, ln_b, W2, b2, out);
}